// Round 6
// baseline (261.868 us; speedup 1.0000x reference)
//
#include <hip/hip_runtime.h>

// Gated delta-rule recurrent cell, single step. B=128, H=16, Dk=Dv=128.
//
// Round-5b: TWO-PASS split (round-5 resubmit; scratch moved from d_ws to
// static __device__ globals after the d_ws write plausibly killed the
// container -- ws_size was never validated).
//
// Rationale: rounds 0-4 (5 structures, occupancy 9-70%, scattered/contiguous,
// pipelined or not) all pinned at 2.4-2.7 TB/s, and round 4 showed duration
// is INVARIANT to whether S reads hit HBM or L3 => not read-BW-bound.
// Common factor: stores depend on a full k-reduction over the loads, so the
// chip runs a phase-locked convoy (all-load / drain / all-store); read and
// write streams never overlap. Fix: split into two kernels, each shaped like
// a known >6 TB/s kernel:
//   P1 reduce:  pure READ stream of S -> delta[bh][v], decay[bh], out head
//               (writes ~1 MB). Leaves S L3-resident (134 MB < 256 MB L3).
//   P2 rewrite: pure grid-stride copy+FMA: S'[i]=decay*S[i]+k[row]*delta[col]
//               1 f4 load (mostly L3 hits) + 1 f4 nt-store per iter, zero
//               cross-lane dependencies -- fillBuffer/copy profile.
// out[v] = decay*Bq[v] + (k.q)*delta[v]  (algebraic identity)

#define DK 128
#define DV 128
#define BH_MAX 2048
typedef float f4 __attribute__((ext_vector_type(4)));

// Inter-pass scratch: static device globals (no hipMalloc, no d_ws).
__device__ float g_delta[BH_MAX * DV];
__device__ float g_decay[BH_MAX];

// ---------------- Pass 1: reduce (one block per (b,h)) ----------------
__global__ __launch_bounds__(256) void s1_reduce_kernel(
    const float* __restrict__ q,
    const float* __restrict__ k,
    const float* __restrict__ v,
    const float* __restrict__ g,
    const float* __restrict__ beta,
    const float* __restrict__ S,
    float* __restrict__ out)        // d_out head: out[bh][v]
{
    const int bh   = blockIdx.x;
    const int w    = threadIdx.x >> 6;     // wave 0..3 -> rows [32w,32w+32)
    const int lane = threadIdx.x & 63;
    const int half = lane >> 5;            // row parity within pair
    const int c0   = (lane & 31) * 4;      // column (float idx)

    __shared__ float apart[4][DV];
    __shared__ float bpart[4][DV];
    __shared__ float skq[4];

    const float* __restrict__ Sb = S + (size_t)bh * (DK * DV);
    const int r0 = 32 * w + half;

    // contiguous 1KB wave loads: rows r0+2i (row pair fully covered)
    f4 s[16];
    #pragma unroll
    for (int i = 0; i < 16; ++i)
        s[i] = *(const f4*)(Sb + (size_t)(r0 + 2 * i) * DV + c0);

    float kv[16], qv[16];
    #pragma unroll
    for (int i = 0; i < 16; ++i) {
        kv[i] = k[bh * DK + r0 + 2 * i];
        qv[i] = q[bh * DK + r0 + 2 * i];
    }

    const float decay = expf(g[bh]);
    const float bta   = beta[bh];

    f4 a = {0.f, 0.f, 0.f, 0.f};
    f4 b = {0.f, 0.f, 0.f, 0.f};
    float kqp = 0.f;
    #pragma unroll
    for (int i = 0; i < 16; ++i) {
        a   += s[i] * kv[i];
        b   += s[i] * qv[i];
        kqp += kv[i] * qv[i];
    }

    // merge row parities (lane ^ 32)
    a.x += __shfl_xor(a.x, 32, 64);  a.y += __shfl_xor(a.y, 32, 64);
    a.z += __shfl_xor(a.z, 32, 64);  a.w += __shfl_xor(a.w, 32, 64);
    b.x += __shfl_xor(b.x, 32, 64);  b.y += __shfl_xor(b.y, 32, 64);
    b.z += __shfl_xor(b.z, 32, 64);  b.w += __shfl_xor(b.w, 32, 64);
    kqp += __shfl_xor(kqp, 32, 64);

    if (lane < 32) {
        *(f4*)&apart[w][c0] = a;
        *(f4*)&bpart[w][c0] = b;
        if (lane == 0) skq[w] = kqp;
    }
    __syncthreads();

    if (w == 0 && lane < 32) {
        f4 A  = *(const f4*)&apart[0][c0];
        f4 Bq = *(const f4*)&bpart[0][c0];
        #pragma unroll
        for (int j = 1; j < 4; ++j) {
            A  += *(const f4*)&apart[j][c0];
            Bq += *(const f4*)&bpart[j][c0];
        }
        const float kq = skq[0] + skq[1] + skq[2] + skq[3];

        const f4 vv  = *(const f4*)(v + bh * DV + c0);
        const f4 dlt = (vv - decay * A) * bta;

        *(f4*)(g_delta + (size_t)bh * DV + c0) = dlt;
        *(f4*)(out + (size_t)bh * DV + c0)     = decay * Bq + kq * dlt;
        if (lane == 0) g_decay[bh] = decay;
    }
}

// ---------------- Pass 2: rewrite (pure copy+FMA stream) ----------------
__global__ __launch_bounds__(256) void s1_rewrite_kernel(
    const float* __restrict__ k,
    const float* __restrict__ S,
    float* __restrict__ outS,       // d_out + BH*DV
    size_t total_f4)                // BH*DK*DV/4
{
    const size_t stride = (size_t)gridDim.x * blockDim.x;
    size_t idx = (size_t)blockIdx.x * blockDim.x + threadIdx.x;

    // stride is a multiple of 4096 f4 (= one tile), so rem/row/col are
    // loop-invariant per thread; only bh advances.
    const int rem = (int)(idx & 4095);
    const int row = rem >> 5;            // k-row 0..127
    const int vc  = (rem & 31) * 4;      // v-col float idx

    for (; idx < total_f4; idx += stride) {
        const int bh = (int)(idx >> 12);
        const f4    s   = *(const f4*)(S + (idx << 2));
        const float dec = g_decay[bh];
        const float kvv = k[bh * DK + row];
        const f4    dlt = *(const f4*)(g_delta + (size_t)bh * DV + vc);
        __builtin_nontemporal_store(dec * s + kvv * dlt,
                                    (f4*)(outS + (idx << 2)));
    }
}

extern "C" void kernel_launch(void* const* d_in, const int* in_sizes, int n_in,
                              void* d_out, int out_size, void* d_ws, size_t ws_size,
                              hipStream_t stream) {
    const float* q    = (const float*)d_in[0];
    const float* k    = (const float*)d_in[1];
    const float* v    = (const float*)d_in[2];
    const float* g    = (const float*)d_in[3];
    const float* beta = (const float*)d_in[4];
    const float* S    = (const float*)d_in[5];
    float* out = (float*)d_out;

    const int BH = in_sizes[3];   // g has B*H elements = 2048 (<= BH_MAX)

    s1_reduce_kernel<<<BH, 256, 0, stream>>>(q, k, v, g, beta, S, out);

    const size_t total_f4 = (size_t)BH * (DK * DV / 4);
    // 4096 blocks x 256 thr: stride = 2^20 f4 = 256 tiles; 8 iters at BH=2048
    s1_rewrite_kernel<<<4096, 256, 0, stream>>>(k, S,
                                                out + (size_t)BH * DV,
                                                total_f4);
}